// Round 8
// baseline (117.883 us; speedup 1.0000x reference)
//
#include <hip/hip_runtime.h>
#include <hip/hip_bf16.h>

// Problem constants (match reference)
#define BATCH 4096
#define NC    1024   // n_concepts (K)
#define NL    512    // n_lemmas   (N)
#define TSTEPS 50
#define GAMMA_C 0.95f
#define KAPPA_C 0.1f
#define FLOOR_C 1e-6f

typedef __attribute__((ext_vector_type(8))) short short8;  // 8 bf16 = 4 VGPRs
typedef __attribute__((ext_vector_type(4))) float f32x4;   // MFMA C/D frag

// ---------------- split fp32 -> bf16 hi + bf16 lo (RNE both) ----------------
__device__ inline void split_bf16(float x, unsigned short& h, unsigned short& l) {
    unsigned u = __float_as_uint(x);
    unsigned rh = u + 0x7FFFu + ((u >> 16) & 1u);
    h = (unsigned short)(rh >> 16);
    float hf = __uint_as_float((unsigned)h << 16);
    float r = x - hf;
    unsigned v = __float_as_uint(r);
    unsigned rl = v + 0x7FFFu + ((v >> 16) & 1u);
    l = (unsigned short)(rl >> 16);
}

// One pass over A (4096x1024) then W (512x1024): float4 in, ushort4 hi+lo out
__global__ __launch_bounds__(256)
void convert_split(const float* __restrict__ A, const float* __restrict__ W,
                   unsigned short* __restrict__ Ahi, unsigned short* __restrict__ Alo,
                   unsigned short* __restrict__ Whi, unsigned short* __restrict__ Wlo) {
    const int chunk = blockIdx.x * 256 + threadIdx.x;
    const int fidx  = chunk * 4;
    const float* src;
    unsigned short *dh, *dl;
    if (fidx < BATCH * NC) {
        src = A + fidx; dh = Ahi + fidx; dl = Alo + fidx;
    } else {
        const int o = fidx - BATCH * NC;
        src = W + o; dh = Whi + o; dl = Wlo + o;
    }
    const float4 v = *(const float4*)src;
    ushort4 h4, l4;
    split_bf16(v.x, h4.x, l4.x);
    split_bf16(v.y, h4.y, l4.y);
    split_bf16(v.z, h4.z, l4.z);
    split_bf16(v.w, h4.w, l4.w);
    *(ushort4*)dh = h4;
    *(ushort4*)dl = l4;
}

// ---------------- async global->LDS, 16 B per lane ----------------
// LDS dest is wave-uniform base + lane*16 (m104/m108); global addr per-lane.
__device__ __forceinline__ void gld_lds16(const void* g, void* l) {
    __builtin_amdgcn_global_load_lds(
        (const __attribute__((address_space(1))) unsigned int*)g,
        (__attribute__((address_space(3))) unsigned int*)l,
        16, 0, 0);
}

// ------------- MFMA GEMM: D = Ahi*Whi^T + Ahi*Wlo^T + Alo*Whi^T -------------
// m97-style staging: global_load_lds width=16 into UNPADDED row-major LDS
// (row stride 32 shorts = 64 B). Lane l of wave-load i lands at i*1024+l*16
// == (row = i*16 + (l>>2)) * 64 + (l&3)*16 -> exactly A/B fragment order.
// Block 128x128, 256 thr = 4 waves (2x2), wave-tile 64x64, GK=32, splitK=2.
// LDS 32 KB -> 4-5 blocks/CU co-resident.
#define TM 128
#define TN 128
#define GK 32

__global__ __launch_bounds__(256)
void gemm_bf16x2(const unsigned short* __restrict__ Ahi, const unsigned short* __restrict__ Alo,
                 const unsigned short* __restrict__ Whi, const unsigned short* __restrict__ Wlo,
                 float* __restrict__ Dp, int kPerSplit) {
    __shared__ unsigned short AsH[TM * GK];   // 8 KB
    __shared__ unsigned short AsL[TM * GK];   // 8 KB
    __shared__ unsigned short BsH[TN * GK];   // 8 KB
    __shared__ unsigned short BsL[TN * GK];   // 8 KB

    const int tid = threadIdx.x;
    const int m0 = blockIdx.x * TM;
    const int n0 = blockIdx.y * TN;
    const int kb = blockIdx.z * kPerSplit;

    const int lane = tid & 63;
    const int w    = tid >> 6;          // 4 waves

    // staging: wave w covers tile rows [w*32, w*32+32) via wave-loads i=w*2+j
    const int lr = lane >> 2;           // 0..15: row within wave-load
    const int lk = (lane & 3) * 8;      // short offset within row

    // wave layout: 2(M) x 2(N), wave-tile 64x64
    const int mw   = (w >> 1) * 64;
    const int nw   = (w & 1) * 64;
    const int sr   = lane & 15;
    const int quad = lane >> 4;

    const unsigned short* rAh = AsH + (mw + sr) * GK + quad * 8;
    const unsigned short* rAl = AsL + (mw + sr) * GK + quad * 8;
    const unsigned short* rBh = BsH + (nw + sr) * GK + quad * 8;
    const unsigned short* rBl = BsL + (nw + sr) * GK + quad * 8;

    f32x4 acc[4][4];
    #pragma unroll
    for (int i = 0; i < 4; ++i)
        #pragma unroll
        for (int j = 0; j < 4; ++j)
            acc[i][j] = (f32x4){0.f, 0.f, 0.f, 0.f};

    for (int kt = 0; kt < kPerSplit; kt += GK) {
        __syncthreads();    // prev compute done reading LDS
        const size_t ko = (size_t)(kb + kt);
        #pragma unroll
        for (int j = 0; j < 2; ++j) {
            const int i16 = w * 2 + j;
            const size_t ga = (size_t)(m0 + i16 * 16 + lr) * NC + ko + lk;
            const size_t gb = (size_t)(n0 + i16 * 16 + lr) * NC + ko + lk;
            gld_lds16(Ahi + ga, AsH + i16 * 512);
            gld_lds16(Alo + ga, AsL + i16 * 512);
            gld_lds16(Whi + gb, BsH + i16 * 512);
            gld_lds16(Wlo + gb, BsL + i16 * 512);
        }
        __syncthreads();    // drains vmcnt(0): loads landed

        short8 afh[4], afl[4], bfh[4], bfl[4];
        #pragma unroll
        for (int mi = 0; mi < 4; ++mi) {
            afh[mi] = *(const short8*)(rAh + mi * 16 * GK);
            afl[mi] = *(const short8*)(rAl + mi * 16 * GK);
        }
        #pragma unroll
        for (int ni = 0; ni < 4; ++ni) {
            bfh[ni] = *(const short8*)(rBh + ni * 16 * GK);
            bfl[ni] = *(const short8*)(rBl + ni * 16 * GK);
        }

        // 48 MFMAs: 16 sites x (hi*hi + hi*lo + lo*hi)
        #pragma unroll
        for (int mi = 0; mi < 4; ++mi) {
            #pragma unroll
            for (int ni = 0; ni < 4; ++ni) {
                acc[mi][ni] = __builtin_amdgcn_mfma_f32_16x16x32_bf16(
                    afh[mi], bfh[ni], acc[mi][ni], 0, 0, 0);
                acc[mi][ni] = __builtin_amdgcn_mfma_f32_16x16x32_bf16(
                    afh[mi], bfl[ni], acc[mi][ni], 0, 0, 0);
                acc[mi][ni] = __builtin_amdgcn_mfma_f32_16x16x32_bf16(
                    afl[mi], bfh[ni], acc[mi][ni], 0, 0, 0);
            }
        }
    }

    // epilogue: C/D layout col = lane&15, row = quad*4 + reg  [m89/m91]
    float* Dz = Dp + (size_t)blockIdx.z * BATCH * NL;
    #pragma unroll
    for (int mi = 0; mi < 4; ++mi) {
        #pragma unroll
        for (int ni = 0; ni < 4; ++ni) {
            const int col = n0 + nw + ni * 16 + sr;
            #pragma unroll
            for (int r = 0; r < 4; ++r) {
                const int row = m0 + mw + mi * 16 + quad * 4 + r;
                Dz[(size_t)row * NL + col] = acc[mi][ni][r];
            }
        }
    }
}

// ------ 50-step recurrence + selection: 64 lanes per row, 8 cols/lane -------
template<int SK>
__global__ __launch_bounds__(256)
void iterate_select(const float* __restrict__ Dp,
                    float* __restrict__ a_out,
                    float* __restrict__ sel_out, float* __restrict__ conf_out) {
    const int lane = threadIdx.x & 63;
    const int wave = threadIdx.x >> 6;
    const int row  = blockIdx.x * 4 + wave;

    float d[8];
    {
        const float4* p0 = (const float4*)(Dp + (size_t)row * NL + lane * 8);
        float4 v0 = p0[0], v1 = p0[1];
        d[0] = v0.x; d[1] = v0.y; d[2] = v0.z; d[3] = v0.w;
        d[4] = v1.x; d[5] = v1.y; d[6] = v1.z; d[7] = v1.w;
        #pragma unroll
        for (int s = 1; s < SK; ++s) {
            const float4* ps = (const float4*)(Dp + (size_t)s * BATCH * NL
                                               + (size_t)row * NL + lane * 8);
            const float4 w0 = ps[0], w1 = ps[1];
            d[0] += w0.x; d[1] += w0.y; d[2] += w0.z; d[3] += w0.w;
            d[4] += w1.x; d[5] += w1.y; d[6] += w1.z; d[7] += w1.w;
        }
    }

    float a[8];
    #pragma unroll
    for (int j = 0; j < 8; ++j) a[j] = 0.f;

    const float K1 = 1.0f + KAPPA_C;

    for (int t = 0; t < TSTEPS; ++t) {
        #pragma unroll
        for (int j = 0; j < 8; ++j) a[j] = fmaf(GAMMA_C, a[j], d[j]);

        float t4a = a[0] + a[4], t4b = a[1] + a[5], t4c = a[2] + a[6], t4d = a[3] + a[7];
        float t2a = t4a + t4c, t2b = t4b + t4d;
        float S = t2a + t2b;

        S += __shfl_xor(S, 1, 64);
        S += __shfl_xor(S, 2, 64);
        S += __shfl_xor(S, 4, 64);
        S += __shfl_xor(S, 8, 64);
        S += __shfl_xor(S, 16, 64);
        S += __shfl_xor(S, 32, 64);

        const float h = -KAPPA_C * S;
        #pragma unroll
        for (int j = 0; j < 8; ++j) {
            const float v = fmaf(K1, a[j], h);
            a[j] = v > 0.f ? v : 0.f;
        }
    }

    float m4a = fmaxf(a[0], a[4]), m4b = fmaxf(a[1], a[5]);
    float m4c = fmaxf(a[2], a[6]), m4d = fmaxf(a[3], a[7]);
    float peak = fmaxf(fmaxf(m4a, m4b), fmaxf(m4c, m4d));
    float s4a = a[0] + a[4], s4b = a[1] + a[5], s4c = a[2] + a[6], s4d = a[3] + a[7];
    float ssum = (s4a + s4b) + (s4c + s4d);

    #pragma unroll
    for (int m = 1; m < 64; m <<= 1) {
        peak = fmaxf(peak, __shfl_xor(peak, m, 64));
        ssum += __shfl_xor(ssum, m, 64);
    }

    const float mean = ssum * (1.0f / (float)NL);
    const float conf = peak / fmaxf(mean, FLOOR_C);

    int idx = 0x7fffffff;
    #pragma unroll
    for (int j = 0; j < 8; ++j)
        if (a[j] == peak) idx = min(idx, lane * 8 + j);
    #pragma unroll
    for (int m = 1; m < 64; m <<= 1)
        idx = min(idx, __shfl_xor(idx, m, 64));

    float4* ar = (float4*)(a_out + (size_t)row * NL + lane * 8);
    float4 o0, o1;
    o0.x = a[0]; o0.y = a[1]; o0.z = a[2]; o0.w = a[3];
    o1.x = a[4]; o1.y = a[5]; o1.z = a[6]; o1.w = a[7];
    ar[0] = o0; ar[1] = o1;

    if (lane == 0) {
        if (sel_out)  sel_out[row]  = (float)idx;
        if (conf_out) conf_out[row] = conf;
    }
}

extern "C" void kernel_launch(void* const* d_in, const int* in_sizes, int n_in,
                              void* d_out, int out_size, void* d_ws, size_t ws_size,
                              hipStream_t stream) {
    const float* c_lex = (const float*)d_in[0];
    const float* W     = (const float*)d_in[1];
    // d_in[2] = a0 (zeros at every reset; recurrence inits a=0 directly)

    // workspace: 2 D-partials (16.8 MB) + Ahi/Alo (16.8 MB) + Whi/Wlo (2.1 MB)
    float* D = (float*)d_ws;
    unsigned short* Ahi = (unsigned short*)(D + 2ull * BATCH * NL);
    unsigned short* Alo = Ahi + (size_t)BATCH * NC;
    unsigned short* Whi = Alo + (size_t)BATCH * NC;
    unsigned short* Wlo = Whi + (size_t)NL * NC;

    float* a_out = (float*)d_out;
    float* sel   = nullptr;
    float* conf  = nullptr;
    const int base = BATCH * NL;
    if (out_size >= base + 2 * BATCH) {        // (a, selected, confidence)
        sel  = a_out + base;
        conf = a_out + base + BATCH;
    } else if (out_size >= base + BATCH) {     // (a, confidence)
        conf = a_out + base;
    }

    // 1) fp32 -> bf16 hi/lo for A and W
    convert_split<<<dim3(4608), 256, 0, stream>>>(c_lex, W, Ahi, Alo, Whi, Wlo);

    // 2) MFMA GEMM with global_load_lds staging, splitK=2: grid (32,4,2)
    const int kPerSplit = NC / 2;
    gemm_bf16x2<<<dim3(BATCH / TM, NL / TN, 2), 256, 0, stream>>>(
        Ahi, Alo, Whi, Wlo, D, kPerSplit);

    // 3) recurrence + selection: 1 row/wave, 4 waves/SIMD
    iterate_select<2><<<dim3(BATCH / 4), 256, 0, stream>>>(D, a_out, sel, conf);
}

// Round 9
// 114.317 us; speedup vs baseline: 1.0312x; 1.0312x over previous
//
#include <hip/hip_runtime.h>
#include <hip/hip_bf16.h>

// Problem constants (match reference)
#define BATCH 4096
#define NC    1024   // n_concepts (K)
#define NL    512    // n_lemmas   (N)
#define TSTEPS 50
#define GAMMA_C 0.95f
#define KAPPA_C 0.1f
#define FLOOR_C 1e-6f

typedef __attribute__((ext_vector_type(8))) short short8;  // 8 bf16 = 4 VGPRs
typedef __attribute__((ext_vector_type(4))) float f32x4;   // MFMA C/D frag

// ---------------- split fp32 -> bf16 hi + bf16 lo (RNE both) ----------------
__device__ inline void split_bf16(float x, unsigned short& h, unsigned short& l) {
    unsigned u = __float_as_uint(x);
    unsigned rh = u + 0x7FFFu + ((u >> 16) & 1u);
    h = (unsigned short)(rh >> 16);
    float hf = __uint_as_float((unsigned)h << 16);
    float r = x - hf;
    unsigned v = __float_as_uint(r);
    unsigned rl = v + 0x7FFFu + ((v >> 16) & 1u);
    l = (unsigned short)(rl >> 16);
}

// One pass over A (4096x1024) then W (512x1024): float4 in, ushort4 hi+lo out
__global__ __launch_bounds__(256)
void convert_split(const float* __restrict__ A, const float* __restrict__ W,
                   unsigned short* __restrict__ Ahi, unsigned short* __restrict__ Alo,
                   unsigned short* __restrict__ Whi, unsigned short* __restrict__ Wlo) {
    const int chunk = blockIdx.x * 256 + threadIdx.x;
    const int fidx  = chunk * 4;
    const float* src;
    unsigned short *dh, *dl;
    if (fidx < BATCH * NC) {
        src = A + fidx; dh = Ahi + fidx; dl = Alo + fidx;
    } else {
        const int o = fidx - BATCH * NC;
        src = W + o; dh = Whi + o; dl = Wlo + o;
    }
    const float4 v = *(const float4*)src;
    ushort4 h4, l4;
    split_bf16(v.x, h4.x, l4.x);
    split_bf16(v.y, h4.y, l4.y);
    split_bf16(v.z, h4.z, l4.z);
    split_bf16(v.w, h4.w, l4.w);
    *(ushort4*)dh = h4;
    *(ushort4*)dl = l4;
}

// ---------------- async global->LDS, 16 B per lane ----------------
// LDS dest is wave-uniform base + lane*16 (m104/m108); global addr per-lane.
__device__ __forceinline__ void gld_lds16(const void* g, void* l) {
    __builtin_amdgcn_global_load_lds(
        (const __attribute__((address_space(1))) unsigned int*)g,
        (__attribute__((address_space(3))) unsigned int*)l,
        16, 0, 0);
}

// ------------- MFMA GEMM: D = Ahi*Whi^T + Ahi*Wlo^T + Alo*Whi^T -------------
// DOUBLE-BUFFERED global_load_lds staging, ONE barrier per stage:
//   issue loads(s+1 -> buf^1); ds_read+MFMA from buf; __syncthreads (drains
//   loads that had the whole compute phase in flight -> ~zero stall).
// Unpadded row-major LDS (row stride 32 shorts = 64 B): lane l of wave-load
// i lands at i*1024B + l*16B == row i*16+(l>>2), chunk (l&3)*16B -> exactly
// the MFMA fragment order. Block 128x128, 256 thr = 4 waves (2x2), wave-tile
// 64x64, GK=32. splitK=4 -> grid (32,4,4) = 512 blocks = 2/CU (64 KB LDS).
#define TM 128
#define TN 128
#define GK 32

__global__ __launch_bounds__(256)
void gemm_bf16x2(const unsigned short* __restrict__ Ahi, const unsigned short* __restrict__ Alo,
                 const unsigned short* __restrict__ Whi, const unsigned short* __restrict__ Wlo,
                 float* __restrict__ Dp, int kPerSplit) {
    __shared__ unsigned short AsH[2][TM * GK];   // 2 x 8 KB
    __shared__ unsigned short AsL[2][TM * GK];
    __shared__ unsigned short BsH[2][TN * GK];
    __shared__ unsigned short BsL[2][TN * GK];

    const int tid = threadIdx.x;
    const int m0 = blockIdx.x * TM;
    const int n0 = blockIdx.y * TN;
    const int kb = blockIdx.z * kPerSplit;

    const int lane = tid & 63;
    const int w    = tid >> 6;          // 4 waves

    // staging: wave w covers tile rows [w*32, w*32+32) via wave-loads i=w*2+j
    const int lr = lane >> 2;           // 0..15: row within wave-load
    const int lk = (lane & 3) * 8;      // short offset within row

    // wave layout: 2(M) x 2(N), wave-tile 64x64
    const int mw   = (w >> 1) * 64;
    const int nw   = (w & 1) * 64;
    const int sr   = lane & 15;
    const int quad = lane >> 4;

    f32x4 acc[4][4];
    #pragma unroll
    for (int i = 0; i < 4; ++i)
        #pragma unroll
        for (int j = 0; j < 4; ++j)
            acc[i][j] = (f32x4){0.f, 0.f, 0.f, 0.f};

    // issue loads for a stage into buffer `buf`
    #define ISSUE_STAGE(ko, buf)                                                  \
        {                                                                         \
            _Pragma("unroll")                                                     \
            for (int j = 0; j < 2; ++j) {                                         \
                const int i16 = w * 2 + j;                                        \
                const size_t ga = (size_t)(m0 + i16 * 16 + lr) * NC + (ko) + lk;  \
                const size_t gb = (size_t)(n0 + i16 * 16 + lr) * NC + (ko) + lk;  \
                gld_lds16(Ahi + ga, &AsH[buf][i16 * 512]);                        \
                gld_lds16(Alo + ga, &AsL[buf][i16 * 512]);                        \
                gld_lds16(Whi + gb, &BsH[buf][i16 * 512]);                        \
                gld_lds16(Wlo + gb, &BsL[buf][i16 * 512]);                        \
            }                                                                     \
        }

    const int nst = kPerSplit / GK;

    ISSUE_STAGE(kb, 0);
    __syncthreads();                    // stage 0 landed

    for (int s = 0; s < nst; ++s) {
        const int cur = s & 1;
        if (s + 1 < nst)
            ISSUE_STAGE(kb + (s + 1) * GK, cur ^ 1);   // in flight during compute

        const unsigned short* rAh = &AsH[cur][(mw + sr) * GK + quad * 8];
        const unsigned short* rAl = &AsL[cur][(mw + sr) * GK + quad * 8];
        const unsigned short* rBh = &BsH[cur][(nw + sr) * GK + quad * 8];
        const unsigned short* rBl = &BsL[cur][(nw + sr) * GK + quad * 8];

        short8 afh[4], afl[4], bfh[4], bfl[4];
        #pragma unroll
        for (int mi = 0; mi < 4; ++mi) {
            afh[mi] = *(const short8*)(rAh + mi * 16 * GK);
            afl[mi] = *(const short8*)(rAl + mi * 16 * GK);
        }
        #pragma unroll
        for (int ni = 0; ni < 4; ++ni) {
            bfh[ni] = *(const short8*)(rBh + ni * 16 * GK);
            bfl[ni] = *(const short8*)(rBl + ni * 16 * GK);
        }

        // 48 MFMAs: 16 sites x (hi*hi + hi*lo + lo*hi)
        #pragma unroll
        for (int mi = 0; mi < 4; ++mi) {
            #pragma unroll
            for (int ni = 0; ni < 4; ++ni) {
                acc[mi][ni] = __builtin_amdgcn_mfma_f32_16x16x32_bf16(
                    afh[mi], bfh[ni], acc[mi][ni], 0, 0, 0);
                acc[mi][ni] = __builtin_amdgcn_mfma_f32_16x16x32_bf16(
                    afh[mi], bfl[ni], acc[mi][ni], 0, 0, 0);
                acc[mi][ni] = __builtin_amdgcn_mfma_f32_16x16x32_bf16(
                    afl[mi], bfh[ni], acc[mi][ni], 0, 0, 0);
            }
        }

        __syncthreads();   // drains next-stage loads (fully overlapped) +
                           // guards cur buffer reuse
    }

    // epilogue: C/D layout col = lane&15, row = quad*4 + reg  [m89/m91]
    float* Dz = Dp + (size_t)blockIdx.z * BATCH * NL;
    #pragma unroll
    for (int mi = 0; mi < 4; ++mi) {
        #pragma unroll
        for (int ni = 0; ni < 4; ++ni) {
            const int col = n0 + nw + ni * 16 + sr;
            #pragma unroll
            for (int r = 0; r < 4; ++r) {
                const int row = m0 + mw + mi * 16 + quad * 4 + r;
                Dz[(size_t)row * NL + col] = acc[mi][ni][r];
            }
        }
    }
}

// ------ 50-step recurrence + selection: 64 lanes per row, 8 cols/lane -------
template<int SK>
__global__ __launch_bounds__(256)
void iterate_select(const float* __restrict__ Dp,
                    float* __restrict__ a_out,
                    float* __restrict__ sel_out, float* __restrict__ conf_out) {
    const int lane = threadIdx.x & 63;
    const int wave = threadIdx.x >> 6;
    const int row  = blockIdx.x * 4 + wave;

    float d[8];
    {
        const float4* p0 = (const float4*)(Dp + (size_t)row * NL + lane * 8);
        float4 v0 = p0[0], v1 = p0[1];
        d[0] = v0.x; d[1] = v0.y; d[2] = v0.z; d[3] = v0.w;
        d[4] = v1.x; d[5] = v1.y; d[6] = v1.z; d[7] = v1.w;
        #pragma unroll
        for (int s = 1; s < SK; ++s) {
            const float4* ps = (const float4*)(Dp + (size_t)s * BATCH * NL
                                               + (size_t)row * NL + lane * 8);
            const float4 w0 = ps[0], w1 = ps[1];
            d[0] += w0.x; d[1] += w0.y; d[2] += w0.z; d[3] += w0.w;
            d[4] += w1.x; d[5] += w1.y; d[6] += w1.z; d[7] += w1.w;
        }
    }

    float a[8];
    #pragma unroll
    for (int j = 0; j < 8; ++j) a[j] = 0.f;

    const float K1 = 1.0f + KAPPA_C;

    for (int t = 0; t < TSTEPS; ++t) {
        #pragma unroll
        for (int j = 0; j < 8; ++j) a[j] = fmaf(GAMMA_C, a[j], d[j]);

        float t4a = a[0] + a[4], t4b = a[1] + a[5], t4c = a[2] + a[6], t4d = a[3] + a[7];
        float t2a = t4a + t4c, t2b = t4b + t4d;
        float S = t2a + t2b;

        S += __shfl_xor(S, 1, 64);
        S += __shfl_xor(S, 2, 64);
        S += __shfl_xor(S, 4, 64);
        S += __shfl_xor(S, 8, 64);
        S += __shfl_xor(S, 16, 64);
        S += __shfl_xor(S, 32, 64);

        const float h = -KAPPA_C * S;
        #pragma unroll
        for (int j = 0; j < 8; ++j) {
            const float v = fmaf(K1, a[j], h);
            a[j] = v > 0.f ? v : 0.f;
        }
    }

    float m4a = fmaxf(a[0], a[4]), m4b = fmaxf(a[1], a[5]);
    float m4c = fmaxf(a[2], a[6]), m4d = fmaxf(a[3], a[7]);
    float peak = fmaxf(fmaxf(m4a, m4b), fmaxf(m4c, m4d));
    float s4a = a[0] + a[4], s4b = a[1] + a[5], s4c = a[2] + a[6], s4d = a[3] + a[7];
    float ssum = (s4a + s4b) + (s4c + s4d);

    #pragma unroll
    for (int m = 1; m < 64; m <<= 1) {
        peak = fmaxf(peak, __shfl_xor(peak, m, 64));
        ssum += __shfl_xor(ssum, m, 64);
    }

    const float mean = ssum * (1.0f / (float)NL);
    const float conf = peak / fmaxf(mean, FLOOR_C);

    int idx = 0x7fffffff;
    #pragma unroll
    for (int j = 0; j < 8; ++j)
        if (a[j] == peak) idx = min(idx, lane * 8 + j);
    #pragma unroll
    for (int m = 1; m < 64; m <<= 1)
        idx = min(idx, __shfl_xor(idx, m, 64));

    float4* ar = (float4*)(a_out + (size_t)row * NL + lane * 8);
    float4 o0, o1;
    o0.x = a[0]; o0.y = a[1]; o0.z = a[2]; o0.w = a[3];
    o1.x = a[4]; o1.y = a[5]; o1.z = a[6]; o1.w = a[7];
    ar[0] = o0; ar[1] = o1;

    if (lane == 0) {
        if (sel_out)  sel_out[row]  = (float)idx;
        if (conf_out) conf_out[row] = conf;
    }
}

extern "C" void kernel_launch(void* const* d_in, const int* in_sizes, int n_in,
                              void* d_out, int out_size, void* d_ws, size_t ws_size,
                              hipStream_t stream) {
    const float* c_lex = (const float*)d_in[0];
    const float* W     = (const float*)d_in[1];
    // d_in[2] = a0 (zeros at every reset; recurrence inits a=0 directly)

    // workspace: 4 D-partials (33.6 MB) + Ahi/Alo (16.8 MB) + Whi/Wlo (2.1 MB)
    float* D = (float*)d_ws;
    unsigned short* Ahi = (unsigned short*)(D + 4ull * BATCH * NL);
    unsigned short* Alo = Ahi + (size_t)BATCH * NC;
    unsigned short* Whi = Alo + (size_t)BATCH * NC;
    unsigned short* Wlo = Whi + (size_t)NL * NC;

    float* a_out = (float*)d_out;
    float* sel   = nullptr;
    float* conf  = nullptr;
    const int base = BATCH * NL;
    if (out_size >= base + 2 * BATCH) {        // (a, selected, confidence)
        sel  = a_out + base;
        conf = a_out + base + BATCH;
    } else if (out_size >= base + BATCH) {     // (a, confidence)
        conf = a_out + base;
    }

    // 1) fp32 -> bf16 hi/lo for A and W
    convert_split<<<dim3(4608), 256, 0, stream>>>(c_lex, W, Ahi, Alo, Whi, Wlo);

    // 2) double-buffered MFMA GEMM, splitK=4: grid (32,4,4) = 512 blocks
    const int kPerSplit = NC / 4;
    gemm_bf16x2<<<dim3(BATCH / TM, NL / TN, 4), 256, 0, stream>>>(
        Ahi, Alo, Whi, Wlo, D, kPerSplit);

    // 3) recurrence + selection: 1 row/wave, 4 waves/SIMD
    iterate_select<4><<<dim3(BATCH / 4), 256, 0, stream>>>(D, a_out, sel, conf);
}